// Round 3
// baseline (186.209 us; speedup 1.0000x reference)
//
#include <hip/hip_runtime.h>
#include <stdint.h>

#define IN_DIM 4096
#define H_DIM  2048
#define NPTS   2097152

typedef short  bf16x8  __attribute__((ext_vector_type(8)));
typedef float  floatx4 __attribute__((ext_vector_type(4)));

#define AS1 __attribute__((address_space(1)))
#define AS3 __attribute__((address_space(3)))

__device__ __forceinline__ unsigned short f2bf(float f) {
    unsigned u = __float_as_uint(f);
    unsigned r = (u + 0x7FFFu + ((u >> 16) & 1u)) >> 16;   // RNE
    return (unsigned short)r;
}

// ---------------- Kernel 1: prep_h + prep_w2t merged; also zeros rowsum ----------------
__global__ void prep_all(const float* __restrict__ W1, const float* __restrict__ b1,
                         const float* __restrict__ W2,
                         unsigned short* __restrict__ hbf, unsigned short* __restrict__ W2T,
                         float* __restrict__ rowsum) {
    __shared__ unsigned short tile[64][66];
    int b = blockIdx.x;
    if (b < 8192) {
        if (b < 16) rowsum[b * 256 + threadIdx.x] = 0.0f;   // 16*256 = 4096
        int idx = (b * 256 + threadIdx.x) * 4;              // covers 8388608
        float4 w = *(const float4*)(W1 + idx);
        float4 bb = *(const float4*)(b1 + (idx & (H_DIM - 1)));
        ushort4 o;
        o.x = f2bf(tanhf(w.x + bb.x));
        o.y = f2bf(tanhf(w.y + bb.y));
        o.z = f2bf(tanhf(w.z + bb.z));
        o.w = f2bf(tanhf(w.w + bb.w));
        *(ushort4*)(hbf + idx) = o;
    } else {
        int bb = b - 8192;
        int k0 = (bb >> 5) * 64, n0 = (bb & 31) * 64;
        for (int idx = threadIdx.x; idx < 64 * 64; idx += 256) {
            int r = idx >> 6, c = idx & 63;             // c fast -> coalesced read of W2 row
            tile[c][r] = f2bf(W2[(size_t)(k0 + r) * H_DIM + n0 + c]);
        }
        __syncthreads();
        for (int idx = threadIdx.x; idx < 64 * 64; idx += 256) {
            int r = idx >> 6, c = idx & 63;             // c fast -> coalesced write of W2T row
            W2T[(size_t)(n0 + r) * H_DIM + k0 + c] = tile[r][c];
        }
    }
}

// ---------------- Kernel 2: fused GEMM + tanh + @W3 row-reduce ----------------
// 128x64 tile, 1024 blocks = EXACTLY 4 blocks/CU -- occupancy is sacred here:
//   R1: 128x128 -> 512 blocks (2/CU)  -> 77 us
//   R2: dbuf BK=64 -> 48 KB LDS (3/CU) -> 85 us   (occupancy loss >> pipeline gain)
// This round: BK=32 double-buffer = 24 KB LDS total -> keeps 4/CU AND overlaps
// staging with compute (T3-minimum 2-phase): per tile {STAGE(next buf);
// ds_read+MFMA(cur buf); asm vmcnt(0); raw s_barrier}. 64 barriers (same as R0),
// same total staging instrs & MFMAs; only the drain moves to AFTER compute.
// Staging swizzle (BK=32, 4-chunk variant): per load instr 64 lanes cover 16 rows
// x 64 B. Lane l -> row (l>>2), slot (l&3), FETCHED global chunk (l&3)^((l>>2)&3)
//   -> LDS slot c of row r holds k-chunk c^(r&3); elem(r,k) @ r*32 + ((k>>3)^(r&3))*8 + (k&7)
//   -> fragment ds_read_b128 slot cs = quad^(lane16&3) -> global chunk = quad ✓
//   -> bank check: 8-lane phase group = 8 consecutive rows; byte%128 =
//      (r&1)*64 + cs*16 -> each bank pair hit exactly 2x = free (m136).
#define BK 32
__global__ __launch_bounds__(256, 4) void gemm_fused(
    const unsigned short* __restrict__ A,    // 4096 x 2048 bf16 (h)
    const unsigned short* __restrict__ BT,   // 2048 x 2048 bf16 (W2^T, N x K)
    const float* __restrict__ b2, const float* __restrict__ W3,
    float* __restrict__ rowsum) {
    __shared__ __align__(16) unsigned short As0[128 * BK];  // 8 KB
    __shared__ __align__(16) unsigned short As1[128 * BK];  // 8 KB
    __shared__ __align__(16) unsigned short Bs0[64 * BK];   // 4 KB
    __shared__ __align__(16) unsigned short Bs1[64 * BK];   // 4 KB
    const int K = H_DIM;
    const int t = threadIdx.x;
    const int w = t >> 6, l = t & 63;
    const int lane16 = l & 15, quad = l >> 4;
    const int wr = w >> 1, wc = w & 1;                      // 2x2 waves over 128x64
    const int rowBase = blockIdx.y * 128;
    const int colBase = blockIdx.x * 64;

    // per-lane staging offset within a 16-row group (elements)
    const int sRow = l >> 2;                         // 0..15
    const int sChunk = (l & 3) ^ (sRow & 3);         // swizzled data chunk
    const size_t laneOff = (size_t)sRow * K + sChunk * 8;

    // wave w stages A rows [w*32, w*32+32) in 2 instrs, B rows [w*16, w*16+16) in 1
    const unsigned short* aBase = A  + (size_t)(rowBase + w * 32) * K + laneOff;
    const unsigned short* bBase = BT + (size_t)(colBase + w * 16) * K + laneOff;

    floatx4 acc[4][2];
    floatx4 zero = {0.f, 0.f, 0.f, 0.f};
#pragma unroll
    for (int i = 0; i < 4; ++i)
#pragma unroll
        for (int j = 0; j < 2; ++j) acc[i][j] = zero;

#define STAGE(AsB, BsB, k0)                                                    \
    {                                                                          \
        _Pragma("unroll")                                                      \
        for (int i = 0; i < 2; ++i)                                            \
            __builtin_amdgcn_global_load_lds(                                  \
                (const AS1 void*)(aBase + (size_t)i * 16 * K + (k0)),          \
                (AS3 void*)(AsB + (w * 32 + i * 16) * BK), 16, 0, 0);          \
        __builtin_amdgcn_global_load_lds(                                      \
            (const AS1 void*)(bBase + (k0)),                                   \
            (AS3 void*)(BsB + (w * 16) * BK), 16, 0, 0);                       \
    }

#define COMPUTE(AsB, BsB)                                                      \
    {                                                                          \
        const int cs = quad ^ (lane16 & 3);                                    \
        bf16x8 af[4], bfr[2];                                                  \
        _Pragma("unroll")                                                      \
        for (int mi = 0; mi < 4; ++mi)                                         \
            af[mi] = *(const bf16x8*)(AsB + (wr * 64 + mi * 16 + lane16) * BK + cs * 8); \
        _Pragma("unroll")                                                      \
        for (int ni = 0; ni < 2; ++ni)                                         \
            bfr[ni] = *(const bf16x8*)(BsB + (wc * 32 + ni * 16 + lane16) * BK + cs * 8); \
        _Pragma("unroll")                                                      \
        for (int mi = 0; mi < 4; ++mi)                                         \
            _Pragma("unroll")                                                  \
            for (int ni = 0; ni < 2; ++ni)                                     \
                acc[mi][ni] = __builtin_amdgcn_mfma_f32_16x16x32_bf16(         \
                    af[mi], bfr[ni], acc[mi][ni], 0, 0, 0);                    \
    }

#define SYNC()                                                                 \
    asm volatile("s_waitcnt vmcnt(0)" ::: "memory");                           \
    __builtin_amdgcn_s_barrier();

    // 64 K-tiles of 32. Prologue: stage tile 0 into buf0.
    STAGE(As0, Bs0, 0);
    SYNC();

    // Main loop: 31 pairs -> stages tiles 1..62, computes 0..61.
    for (int k0 = BK; k0 < 63 * BK; k0 += 2 * BK) {
        STAGE(As1, Bs1, k0);            // odd tile  -> buf1
        COMPUTE(As0, Bs0);
        SYNC();
        STAGE(As0, Bs0, k0 + BK);       // even tile -> buf0
        COMPUTE(As1, Bs1);
        SYNC();
    }
    // Tail: stage tile 63, compute tile 62, then tile 63.
    STAGE(As1, Bs1, 63 * BK);
    COMPUTE(As0, Bs0);
    SYNC();
    COMPUTE(As1, Bs1);

#undef STAGE
#undef COMPUTE
#undef SYNC

    // Epilogue: C/D layout col=lane&15, row=quad*4+reg
    const int rowG = rowBase + wr * 64;
#pragma unroll
    for (int mi = 0; mi < 4; ++mi) {
#pragma unroll
        for (int r = 0; r < 4; ++r) {
            float s = 0.f;
#pragma unroll
            for (int ni = 0; ni < 2; ++ni) {
                int col = colBase + wc * 32 + ni * 16 + lane16;
                float v = acc[mi][ni][r] + b2[col];
                s += tanhf(v) * W3[col];
            }
#pragma unroll
            for (int off = 1; off < 16; off <<= 1) s += __shfl_xor(s, off, 64);
            if (lane16 == 0)
                atomicAdd(&rowsum[rowG + mi * 16 + quad * 4 + r], s);
        }
    }
}

// ---------------- Kernel 3: spline gather, 2 points/thread, fused u=3*tanh(rowsum+b3) ----------------
__device__ __forceinline__ float spline_eval(const float* us, float ptx, float pty) {
    float x = (ptx + 1.0f) * 0.5f;
    float px = x * 62.0f, py = pty * 62.0f;
    float fx = floorf(px), fy = floorf(py);
    int posx = min((int)fx + 1, 62);
    int posy = min((int)fy + 1, 62);
    float tx = px - fx, ty = py - fy;
    float bx0 = 0.5f * (1.f - tx) * (1.f - tx);
    float bx1 = -tx * tx + tx + 0.5f;
    float bx2 = 0.5f * tx * tx;
    float by0 = 0.5f * (1.f - ty) * (1.f - ty);
    float by1 = -ty * ty + ty + 0.5f;
    float by2 = 0.5f * ty * ty;
    const float* r0 = &us[(posx - 1) * 64 + (posy - 1)];
    const float* r1 = r0 + 64;
    const float* r2 = r1 + 64;
    float s0 = r0[0] * by0 + r0[1] * by1 + r0[2] * by2;
    float s1 = r1[0] * by0 + r1[1] * by1 + r1[2] * by2;
    float s2 = r2[0] * by0 + r2[1] * by1 + r2[2] * by2;
    return bx0 * s0 + bx1 * s1 + bx2 * s2;
}

__global__ void spline_kernel(const float4* __restrict__ pts,
                              const float* __restrict__ rowsum,
                              const float* __restrict__ b3,
                              float2* __restrict__ out, int npairs) {
    __shared__ float us[4096];
    float bias = b3[0];
    for (int i = threadIdx.x; i < 4096; i += blockDim.x)
        us[i] = 3.0f * tanhf(rowsum[i] + bias);
    __syncthreads();
    int stride = gridDim.x * blockDim.x;
    for (int idx = blockIdx.x * blockDim.x + threadIdx.x; idx < npairs; idx += stride) {
        float4 p2 = pts[idx];     // two points
        float2 o;
        o.x = spline_eval(us, p2.x, p2.y);
        o.y = spline_eval(us, p2.z, p2.w);
        out[idx] = o;
    }
}

extern "C" void kernel_launch(void* const* d_in, const int* in_sizes, int n_in,
                              void* d_out, int out_size, void* d_ws, size_t ws_size,
                              hipStream_t stream) {
    const float* points = (const float*)d_in[0];
    const float* W1 = (const float*)d_in[1];
    const float* b1 = (const float*)d_in[2];
    const float* W2 = (const float*)d_in[3];
    const float* b2 = (const float*)d_in[4];
    const float* W3 = (const float*)d_in[5];
    const float* b3 = (const float*)d_in[6];
    float* out = (float*)d_out;

    char* ws = (char*)d_ws;
    unsigned short* hbf = (unsigned short*)ws;                        // 16777216 B
    unsigned short* w2t = (unsigned short*)(ws + 16777216);           //  8388608 B
    float* rowsum = (float*)(ws + 25165824);                          //    16384 B

    prep_all<<<8192 + 1024, 256, 0, stream>>>(W1, b1, W2, hbf, w2t, rowsum);
    gemm_fused<<<dim3(H_DIM / 64, IN_DIM / 128), 256, 0, stream>>>(hbf, w2t, b2, W3, rowsum);
    spline_kernel<<<1024, 256, 0, stream>>>((const float4*)points, rowsum, b3,
                                            (float2*)out, NPTS / 2);
}

// Round 4
// 182.863 us; speedup vs baseline: 1.0183x; 1.0183x over previous
//
#include <hip/hip_runtime.h>
#include <stdint.h>

#define IN_DIM 4096
#define H_DIM  2048
#define NPTS   2097152

typedef short  bf16x8  __attribute__((ext_vector_type(8)));
typedef float  floatx4 __attribute__((ext_vector_type(4)));

#define AS1 __attribute__((address_space(1)))
#define AS3 __attribute__((address_space(3)))

__device__ __forceinline__ unsigned short f2bf(float f) {
    unsigned u = __float_as_uint(f);
    unsigned r = (u + 0x7FFFu + ((u >> 16) & 1u)) >> 16;   // RNE
    return (unsigned short)r;
}

// ---------------- Kernel 1: prep_h + prep_w2t merged; also zeros rowsum ----------------
__global__ void prep_all(const float* __restrict__ W1, const float* __restrict__ b1,
                         const float* __restrict__ W2,
                         unsigned short* __restrict__ hbf, unsigned short* __restrict__ W2T,
                         float* __restrict__ rowsum) {
    __shared__ unsigned short tile[64][66];
    int b = blockIdx.x;
    if (b < 8192) {
        if (b < 16) rowsum[b * 256 + threadIdx.x] = 0.0f;   // 16*256 = 4096
        int idx = (b * 256 + threadIdx.x) * 4;              // covers 8388608
        float4 w = *(const float4*)(W1 + idx);
        float4 bb = *(const float4*)(b1 + (idx & (H_DIM - 1)));
        ushort4 o;
        o.x = f2bf(tanhf(w.x + bb.x));
        o.y = f2bf(tanhf(w.y + bb.y));
        o.z = f2bf(tanhf(w.z + bb.z));
        o.w = f2bf(tanhf(w.w + bb.w));
        *(ushort4*)(hbf + idx) = o;
    } else {
        int bb = b - 8192;
        int k0 = (bb >> 5) * 64, n0 = (bb & 31) * 64;
        for (int idx = threadIdx.x; idx < 64 * 64; idx += 256) {
            int r = idx >> 6, c = idx & 63;             // c fast -> coalesced read of W2 row
            tile[c][r] = f2bf(W2[(size_t)(k0 + r) * H_DIM + n0 + c]);
        }
        __syncthreads();
        for (int idx = threadIdx.x; idx < 64 * 64; idx += 256) {
            int r = idx >> 6, c = idx & 63;             // c fast -> coalesced write of W2T row
            W2T[(size_t)(n0 + r) * H_DIM + k0 + c] = tile[r][c];
        }
    }
}

// ---------------- Kernel 2: fused GEMM + tanh + @W3 row-reduce ----------------
// 128x64 tile, 1024 blocks = 4 blocks/CU. BK=32 double-buffer (24 KB LDS) with
// T3 2-phase: per tile {STAGE(next buf); ds_read+MFMA(cur); vmcnt(0); s_barrier}.
// R3 lesson: at BK=32 a row is 64 B = only FOUR 16B chunk slots; swz(r)=r&3 gave
// 8-lane b128 phase groups just 4 distinct slots -> 2-way conflict -> 6.29M
// SQ_LDS_BANK_CONFLICT -> queuing blowup on the ~75%-loaded LDS pipe (77 us).
// FIX: swz(r) = (r>>1)&3. Fragment-read offset within a 128B row-pair is
// (row&1)*64 + cs*16, cs = quad^((lane16>>1)&3); any 8-lane phase group (rows
// p..p+7, parity alternating, (lane16>>1)&3 = 0,0,1,1,2,2,3,3) enumerates
// {0,16,...,112} exactly -> 8 distinct 16B slots, all 32 banks, 0 conflicts.
// Staging: lane l -> row l>>2, slot l&3, fetched chunk (l&3)^((row>>1)&3);
// per-row 4 lanes fetch {0..3}^const = contiguous 64 B ✓ (same involution both
// sides, rule #21; 16-row group bases are multiples of 16 so swz is base-free).
#define BK 32
__global__ __launch_bounds__(256, 4) void gemm_fused(
    const unsigned short* __restrict__ A,    // 4096 x 2048 bf16 (h)
    const unsigned short* __restrict__ BT,   // 2048 x 2048 bf16 (W2^T, N x K)
    const float* __restrict__ b2, const float* __restrict__ W3,
    float* __restrict__ rowsum) {
    __shared__ __align__(16) unsigned short As0[128 * BK];  // 8 KB
    __shared__ __align__(16) unsigned short As1[128 * BK];  // 8 KB
    __shared__ __align__(16) unsigned short Bs0[64 * BK];   // 4 KB
    __shared__ __align__(16) unsigned short Bs1[64 * BK];   // 4 KB
    const int K = H_DIM;
    const int t = threadIdx.x;
    const int w = t >> 6, l = t & 63;
    const int lane16 = l & 15, quad = l >> 4;
    const int wr = w >> 1, wc = w & 1;                      // 2x2 waves over 128x64
    const int rowBase = blockIdx.y * 128;
    const int colBase = blockIdx.x * 64;

    // per-lane staging offset within a 16-row group (elements)
    const int sRow = l >> 2;                         // 0..15
    const int sChunk = (l & 3) ^ ((sRow >> 1) & 3);  // FIXED swizzle: (row>>1)&3
    const size_t laneOff = (size_t)sRow * K + sChunk * 8;

    // wave w stages A rows [w*32, w*32+32) in 2 instrs, B rows [w*16, w*16+16) in 1
    const unsigned short* aBase = A  + (size_t)(rowBase + w * 32) * K + laneOff;
    const unsigned short* bBase = BT + (size_t)(colBase + w * 16) * K + laneOff;

    floatx4 acc[4][2];
    floatx4 zero = {0.f, 0.f, 0.f, 0.f};
#pragma unroll
    for (int i = 0; i < 4; ++i)
#pragma unroll
        for (int j = 0; j < 2; ++j) acc[i][j] = zero;

#define STAGE(AsB, BsB, k0)                                                    \
    {                                                                          \
        _Pragma("unroll")                                                      \
        for (int i = 0; i < 2; ++i)                                            \
            __builtin_amdgcn_global_load_lds(                                  \
                (const AS1 void*)(aBase + (size_t)i * 16 * K + (k0)),          \
                (AS3 void*)(AsB + (w * 32 + i * 16) * BK), 16, 0, 0);          \
        __builtin_amdgcn_global_load_lds(                                      \
            (const AS1 void*)(bBase + (k0)),                                   \
            (AS3 void*)(BsB + (w * 16) * BK), 16, 0, 0);                       \
    }

#define COMPUTE(AsB, BsB)                                                      \
    {                                                                          \
        const int cs = quad ^ ((lane16 >> 1) & 3);                             \
        bf16x8 af[4], bfr[2];                                                  \
        _Pragma("unroll")                                                      \
        for (int mi = 0; mi < 4; ++mi)                                         \
            af[mi] = *(const bf16x8*)(AsB + (wr * 64 + mi * 16 + lane16) * BK + cs * 8); \
        _Pragma("unroll")                                                      \
        for (int ni = 0; ni < 2; ++ni)                                         \
            bfr[ni] = *(const bf16x8*)(BsB + (wc * 32 + ni * 16 + lane16) * BK + cs * 8); \
        _Pragma("unroll")                                                      \
        for (int mi = 0; mi < 4; ++mi)                                         \
            _Pragma("unroll")                                                  \
            for (int ni = 0; ni < 2; ++ni)                                     \
                acc[mi][ni] = __builtin_amdgcn_mfma_f32_16x16x32_bf16(         \
                    af[mi], bfr[ni], acc[mi][ni], 0, 0, 0);                    \
    }

#define SYNC()                                                                 \
    asm volatile("s_waitcnt vmcnt(0)" ::: "memory");                           \
    __builtin_amdgcn_s_barrier();

    // 64 K-tiles of 32. Prologue: stage tile 0 into buf0.
    STAGE(As0, Bs0, 0);
    SYNC();

    // Main loop: 31 pairs -> stages tiles 1..62, computes 0..61.
    for (int k0 = BK; k0 < 63 * BK; k0 += 2 * BK) {
        STAGE(As1, Bs1, k0);            // odd tile  -> buf1
        COMPUTE(As0, Bs0);
        SYNC();
        STAGE(As0, Bs0, k0 + BK);       // even tile -> buf0
        COMPUTE(As1, Bs1);
        SYNC();
    }
    // Tail: stage tile 63, compute tile 62, then tile 63.
    STAGE(As1, Bs1, 63 * BK);
    COMPUTE(As0, Bs0);
    SYNC();
    COMPUTE(As1, Bs1);

#undef STAGE
#undef COMPUTE
#undef SYNC

    // Epilogue: C/D layout col=lane&15, row=quad*4+reg
    const int rowG = rowBase + wr * 64;
#pragma unroll
    for (int mi = 0; mi < 4; ++mi) {
#pragma unroll
        for (int r = 0; r < 4; ++r) {
            float s = 0.f;
#pragma unroll
            for (int ni = 0; ni < 2; ++ni) {
                int col = colBase + wc * 32 + ni * 16 + lane16;
                float v = acc[mi][ni][r] + b2[col];
                s += tanhf(v) * W3[col];
            }
#pragma unroll
            for (int off = 1; off < 16; off <<= 1) s += __shfl_xor(s, off, 64);
            if (lane16 == 0)
                atomicAdd(&rowsum[rowG + mi * 16 + quad * 4 + r], s);
        }
    }
}

// ---------------- Kernel 3: spline gather, 2 points/thread, fused u=3*tanh(rowsum+b3) ----------------
__device__ __forceinline__ float spline_eval(const float* us, float ptx, float pty) {
    float x = (ptx + 1.0f) * 0.5f;
    float px = x * 62.0f, py = pty * 62.0f;
    float fx = floorf(px), fy = floorf(py);
    int posx = min((int)fx + 1, 62);
    int posy = min((int)fy + 1, 62);
    float tx = px - fx, ty = py - fy;
    float bx0 = 0.5f * (1.f - tx) * (1.f - tx);
    float bx1 = -tx * tx + tx + 0.5f;
    float bx2 = 0.5f * tx * tx;
    float by0 = 0.5f * (1.f - ty) * (1.f - ty);
    float by1 = -ty * ty + ty + 0.5f;
    float by2 = 0.5f * ty * ty;
    const float* r0 = &us[(posx - 1) * 64 + (posy - 1)];
    const float* r1 = r0 + 64;
    const float* r2 = r1 + 64;
    float s0 = r0[0] * by0 + r0[1] * by1 + r0[2] * by2;
    float s1 = r1[0] * by0 + r1[1] * by1 + r1[2] * by2;
    float s2 = r2[0] * by0 + r2[1] * by1 + r2[2] * by2;
    return bx0 * s0 + bx1 * s1 + bx2 * s2;
}

__global__ void spline_kernel(const float4* __restrict__ pts,
                              const float* __restrict__ rowsum,
                              const float* __restrict__ b3,
                              float2* __restrict__ out, int npairs) {
    __shared__ float us[4096];
    float bias = b3[0];
    for (int i = threadIdx.x; i < 4096; i += blockDim.x)
        us[i] = 3.0f * tanhf(rowsum[i] + bias);
    __syncthreads();
    int stride = gridDim.x * blockDim.x;
    for (int idx = blockIdx.x * blockDim.x + threadIdx.x; idx < npairs; idx += stride) {
        float4 p2 = pts[idx];     // two points
        float2 o;
        o.x = spline_eval(us, p2.x, p2.y);
        o.y = spline_eval(us, p2.z, p2.w);
        out[idx] = o;
    }
}

extern "C" void kernel_launch(void* const* d_in, const int* in_sizes, int n_in,
                              void* d_out, int out_size, void* d_ws, size_t ws_size,
                              hipStream_t stream) {
    const float* points = (const float*)d_in[0];
    const float* W1 = (const float*)d_in[1];
    const float* b1 = (const float*)d_in[2];
    const float* W2 = (const float*)d_in[3];
    const float* b2 = (const float*)d_in[4];
    const float* W3 = (const float*)d_in[5];
    const float* b3 = (const float*)d_in[6];
    float* out = (float*)d_out;

    char* ws = (char*)d_ws;
    unsigned short* hbf = (unsigned short*)ws;                        // 16777216 B
    unsigned short* w2t = (unsigned short*)(ws + 16777216);           //  8388608 B
    float* rowsum = (float*)(ws + 25165824);                          //    16384 B

    prep_all<<<8192 + 1024, 256, 0, stream>>>(W1, b1, W2, hbf, w2t, rowsum);
    gemm_fused<<<dim3(H_DIM / 64, IN_DIM / 128), 256, 0, stream>>>(hbf, w2t, b2, W3, rowsum);
    spline_kernel<<<1024, 256, 0, stream>>>((const float4*)points, rowsum, b3,
                                            (float2*)out, NPTS / 2);
}

// Round 5
// 170.205 us; speedup vs baseline: 1.0940x; 1.0744x over previous
//
#include <hip/hip_runtime.h>
#include <stdint.h>

#define IN_DIM 4096
#define H_DIM  2048
#define NPTS   2097152

typedef short  bf16x8  __attribute__((ext_vector_type(8)));
typedef float  floatx4 __attribute__((ext_vector_type(4)));

#define AS1 __attribute__((address_space(1)))
#define AS3 __attribute__((address_space(3)))

__device__ __forceinline__ unsigned short f2bf(float f) {
    unsigned u = __float_as_uint(f);
    unsigned r = (u + 0x7FFFu + ((u >> 16) & 1u)) >> 16;   // RNE
    return (unsigned short)r;
}

// ---------------- Kernel 1: prep_h + prep_w2t merged; also zeros rowsum ----------------
__global__ void prep_all(const float* __restrict__ W1, const float* __restrict__ b1,
                         const float* __restrict__ W2,
                         unsigned short* __restrict__ hbf, unsigned short* __restrict__ W2T,
                         float* __restrict__ rowsum) {
    __shared__ unsigned short tile[64][66];
    int b = blockIdx.x;
    if (b < 8192) {
        if (b < 16) rowsum[b * 256 + threadIdx.x] = 0.0f;   // 16*256 = 4096
        int idx = (b * 256 + threadIdx.x) * 4;              // covers 8388608
        float4 w = *(const float4*)(W1 + idx);
        float4 bb = *(const float4*)(b1 + (idx & (H_DIM - 1)));
        ushort4 o;
        o.x = f2bf(tanhf(w.x + bb.x));
        o.y = f2bf(tanhf(w.y + bb.y));
        o.z = f2bf(tanhf(w.z + bb.z));
        o.w = f2bf(tanhf(w.w + bb.w));
        *(ushort4*)(hbf + idx) = o;
    } else {
        int bb = b - 8192;
        int k0 = (bb >> 5) * 64, n0 = (bb & 31) * 64;
        for (int idx = threadIdx.x; idx < 64 * 64; idx += 256) {
            int r = idx >> 6, c = idx & 63;             // c fast -> coalesced read of W2 row
            tile[c][r] = f2bf(W2[(size_t)(k0 + r) * H_DIM + n0 + c]);
        }
        __syncthreads();
        for (int idx = threadIdx.x; idx < 64 * 64; idx += 256) {
            int r = idx >> 6, c = idx & 63;             // c fast -> coalesced write of W2T row
            W2T[(size_t)(n0 + r) * H_DIM + k0 + c] = tile[r][c];
        }
    }
}

// ---------------- Kernel 2: fused GEMM + tanh + @W3 row-reduce ----------------
// REVERTED to the proven R0 body (55 us, 625 TF): 128x64 tile, BK=64,
// single-buffer two-barrier K-loop, 24 KB LDS, 4 blocks/CU. Scheduling ladder
// (R1 128^2 tile / R2 BK=64 dbuf / R3-R4 BK=32 dbuf) all regressed -> structure
// is at its 2-phase-class ceiling (guide m230/m248: 655-682 TF reference).
// NEW (one variable): 2D XCD-region block swizzle. Evidence: FETCH_SIZE 69.8 MB
// vs 24 MB unique inputs (2.9x L2-miss over-fetch). Default round-robin gives
// XCD x blocks with bx===x (mod 8) -> every XCD streams ALL 32 A-panels
// (17 MB/XCD). Remap XCD x to an 8-by x 16-bx region: per-XCD footprint
// A 4 MB + B 4 MB = 8 MB, per-k-step working set ~256 KB << 4 MB L2 ->
// vmcnt(0) drains fill from L2 (~200 cy) instead of L3/HBM (~500-900 cy).
// Bijective: x=bid&7 (HW round-robin), idx=bid>>3; by=(x>>1)*8+(idx>>4),
// bx=(x&1)*16+(idx&15); inverse exists (x=(by>>3)*2+(bx>>4), idx=(by&7)*16+(bx&15)).
// Staging swizzle (proven, 0 conflicts): lane l -> row (l>>3), data chunk (l&7)^(l>>3);
// LDS elem(r,k) @ r*64 + ((k>>3)^(r&7))*8 + (k&7); fragment slot cs=(s*4+quad)^(lane16&7).
#define BK 64
__global__ __launch_bounds__(256, 4) void gemm_fused(
    const unsigned short* __restrict__ A,    // 4096 x 2048 bf16 (h)
    const unsigned short* __restrict__ BT,   // 2048 x 2048 bf16 (W2^T, N x K)
    const float* __restrict__ b2, const float* __restrict__ W3,
    float* __restrict__ rowsum) {
    __shared__ __align__(16) unsigned short As[128 * BK];   // 16 KB
    __shared__ __align__(16) unsigned short Bs[64 * BK];    // 8 KB
    const int K = H_DIM;
    const int t = threadIdx.x;
    const int w = t >> 6, l = t & 63;
    const int lane16 = l & 15, quad = l >> 4;
    const int wr = w >> 1, wc = w & 1;                      // 2x2 waves over 128x64

    // XCD-region swizzle (8 by x 16 bx per XCD)
    const int bid = blockIdx.x;
    const int xcd = bid & 7, idx = bid >> 3;
    const int by = (xcd >> 1) * 8 + (idx >> 4);
    const int bx = (xcd & 1) * 16 + (idx & 15);
    const int rowBase = by * 128;
    const int colBase = bx * 64;

    // per-lane staging offset within an 8-row group (elements)
    const int sRow = l >> 3;                   // 0..7
    const int sChunk = (l & 7) ^ sRow;         // swizzled data chunk
    const size_t laneOff = (size_t)sRow * K + sChunk * 8;

    // wave w stages A rows [w*32, w*32+32) in 4 instrs, B rows [w*16, w*16+16) in 2
    const unsigned short* aBase = A  + (size_t)(rowBase + w * 32) * K + laneOff;
    const unsigned short* bBase = BT + (size_t)(colBase + w * 16) * K + laneOff;

    floatx4 acc[4][2];
    floatx4 zero = {0.f, 0.f, 0.f, 0.f};
#pragma unroll
    for (int i = 0; i < 4; ++i)
#pragma unroll
        for (int j = 0; j < 2; ++j) acc[i][j] = zero;

    for (int k0 = 0; k0 < K; k0 += BK) {
        __syncthreads();          // prior iteration's ds_reads done; LDS reusable
#pragma unroll
        for (int i = 0; i < 4; ++i)
            __builtin_amdgcn_global_load_lds(
                (const AS1 void*)(aBase + (size_t)i * 8 * K + k0),
                (AS3 void*)(As + (w * 32 + i * 8) * 64), 16, 0, 0);
#pragma unroll
        for (int i = 0; i < 2; ++i)
            __builtin_amdgcn_global_load_lds(
                (const AS1 void*)(bBase + (size_t)i * 8 * K + k0),
                (AS3 void*)(Bs + (w * 16 + i * 8) * 64), 16, 0, 0);
        __syncthreads();          // vmcnt(0) drain: tile ready

#pragma unroll
        for (int s = 0; s < 2; ++s) {   // two 16x16x32 k-steps within BK=64
            const int cs = (s * 4 + quad) ^ (lane16 & 7);
            bf16x8 af[4], bfr[2];
#pragma unroll
            for (int mi = 0; mi < 4; ++mi)
                af[mi] = *(const bf16x8*)(As + (wr * 64 + mi * 16 + lane16) * 64 + cs * 8);
#pragma unroll
            for (int ni = 0; ni < 2; ++ni)
                bfr[ni] = *(const bf16x8*)(Bs + (wc * 32 + ni * 16 + lane16) * 64 + cs * 8);
#pragma unroll
            for (int mi = 0; mi < 4; ++mi)
#pragma unroll
                for (int ni = 0; ni < 2; ++ni)
                    acc[mi][ni] = __builtin_amdgcn_mfma_f32_16x16x32_bf16(
                        af[mi], bfr[ni], acc[mi][ni], 0, 0, 0);
        }
    }

    // Epilogue: C/D layout col=lane&15, row=quad*4+reg
    const int rowG = rowBase + wr * 64;
#pragma unroll
    for (int mi = 0; mi < 4; ++mi) {
#pragma unroll
        for (int r = 0; r < 4; ++r) {
            float s = 0.f;
#pragma unroll
            for (int ni = 0; ni < 2; ++ni) {
                int col = colBase + wc * 32 + ni * 16 + lane16;
                float v = acc[mi][ni][r] + b2[col];
                s += tanhf(v) * W3[col];
            }
#pragma unroll
            for (int off = 1; off < 16; off <<= 1) s += __shfl_xor(s, off, 64);
            if (lane16 == 0)
                atomicAdd(&rowsum[rowG + mi * 16 + quad * 4 + r], s);
        }
    }
}

// ---------------- Kernel 3: spline gather, 2 points/thread, fused u=3*tanh(rowsum+b3) ----------------
__device__ __forceinline__ float spline_eval(const float* us, float ptx, float pty) {
    float x = (ptx + 1.0f) * 0.5f;
    float px = x * 62.0f, py = pty * 62.0f;
    float fx = floorf(px), fy = floorf(py);
    int posx = min((int)fx + 1, 62);
    int posy = min((int)fy + 1, 62);
    float tx = px - fx, ty = py - fy;
    float bx0 = 0.5f * (1.f - tx) * (1.f - tx);
    float bx1 = -tx * tx + tx + 0.5f;
    float bx2 = 0.5f * tx * tx;
    float by0 = 0.5f * (1.f - ty) * (1.f - ty);
    float by1 = -ty * ty + ty + 0.5f;
    float by2 = 0.5f * ty * ty;
    const float* r0 = &us[(posx - 1) * 64 + (posy - 1)];
    const float* r1 = r0 + 64;
    const float* r2 = r1 + 64;
    float s0 = r0[0] * by0 + r0[1] * by1 + r0[2] * by2;
    float s1 = r1[0] * by0 + r1[1] * by1 + r1[2] * by2;
    float s2 = r2[0] * by0 + r2[1] * by1 + r2[2] * by2;
    return bx0 * s0 + bx1 * s1 + bx2 * s2;
}

__global__ void spline_kernel(const float4* __restrict__ pts,
                              const float* __restrict__ rowsum,
                              const float* __restrict__ b3,
                              float2* __restrict__ out, int npairs) {
    __shared__ float us[4096];
    float bias = b3[0];
    for (int i = threadIdx.x; i < 4096; i += blockDim.x)
        us[i] = 3.0f * tanhf(rowsum[i] + bias);
    __syncthreads();
    int stride = gridDim.x * blockDim.x;
    for (int idx = blockIdx.x * blockDim.x + threadIdx.x; idx < npairs; idx += stride) {
        float4 p2 = pts[idx];     // two points
        float2 o;
        o.x = spline_eval(us, p2.x, p2.y);
        o.y = spline_eval(us, p2.z, p2.w);
        out[idx] = o;
    }
}

extern "C" void kernel_launch(void* const* d_in, const int* in_sizes, int n_in,
                              void* d_out, int out_size, void* d_ws, size_t ws_size,
                              hipStream_t stream) {
    const float* points = (const float*)d_in[0];
    const float* W1 = (const float*)d_in[1];
    const float* b1 = (const float*)d_in[2];
    const float* W2 = (const float*)d_in[3];
    const float* b2 = (const float*)d_in[4];
    const float* W3 = (const float*)d_in[5];
    const float* b3 = (const float*)d_in[6];
    float* out = (float*)d_out;

    char* ws = (char*)d_ws;
    unsigned short* hbf = (unsigned short*)ws;                        // 16777216 B
    unsigned short* w2t = (unsigned short*)(ws + 16777216);           //  8388608 B
    float* rowsum = (float*)(ws + 25165824);                          //    16384 B

    prep_all<<<8192 + 1024, 256, 0, stream>>>(W1, b1, W2, hbf, w2t, rowsum);
    gemm_fused<<<1024, 256, 0, stream>>>(hbf, w2t, b2, W3, rowsum);
    spline_kernel<<<1024, 256, 0, stream>>>((const float4*)points, rowsum, b3,
                                            (float2*)out, NPTS / 2);
}

// Round 6
// 169.030 us; speedup vs baseline: 1.1016x; 1.0069x over previous
//
#include <hip/hip_runtime.h>
#include <stdint.h>

#define IN_DIM 4096
#define H_DIM  2048
#define NPTS   2097152

typedef short  bf16x8  __attribute__((ext_vector_type(8)));
typedef float  floatx4 __attribute__((ext_vector_type(4)));

#define AS1 __attribute__((address_space(1)))
#define AS3 __attribute__((address_space(3)))

__device__ __forceinline__ unsigned short f2bf(float f) {
    unsigned u = __float_as_uint(f);
    unsigned r = (u + 0x7FFFu + ((u >> 16) & 1u)) >> 16;   // RNE
    return (unsigned short)r;
}

// Fast tanh: tanh(x) = 1 - 2/(exp(2x)+1) via v_exp_f32 + v_rcp_f32 (~4 instrs vs
// OCML's ~100-150 cy branchy routine). Abs error ~3e-7 (both intrinsics ~1 ulp);
// bf16 quantum on h is 4e-3, output tol 1e-3 -> invisible. Saturates exactly:
// x->+inf: exp2->inf, rcp->0 -> 1; x->-inf: exp2->0 -> -1.
__device__ __forceinline__ float tanh_fast(float x) {
    float e = __builtin_amdgcn_exp2f(x * 2.885390081777927f);   // exp(2x)
    return 1.0f - 2.0f * __builtin_amdgcn_rcpf(e + 1.0f);
}

// ---------------- Kernel 1: prep_h + prep_w2t merged; also zeros rowsum ----------------
__global__ void prep_all(const float* __restrict__ W1, const float* __restrict__ b1,
                         const float* __restrict__ W2,
                         unsigned short* __restrict__ hbf, unsigned short* __restrict__ W2T,
                         float* __restrict__ rowsum) {
    __shared__ unsigned short tile[64][66];
    int b = blockIdx.x;
    if (b < 8192) {
        if (b < 16) rowsum[b * 256 + threadIdx.x] = 0.0f;   // 16*256 = 4096
        int idx = (b * 256 + threadIdx.x) * 4;              // covers 8388608
        float4 w = *(const float4*)(W1 + idx);
        float4 bb = *(const float4*)(b1 + (idx & (H_DIM - 1)));
        ushort4 o;
        o.x = f2bf(tanh_fast(w.x + bb.x));
        o.y = f2bf(tanh_fast(w.y + bb.y));
        o.z = f2bf(tanh_fast(w.z + bb.z));
        o.w = f2bf(tanh_fast(w.w + bb.w));
        *(ushort4*)(hbf + idx) = o;
    } else {
        int bb = b - 8192;
        int k0 = (bb >> 5) * 64, n0 = (bb & 31) * 64;
        for (int idx = threadIdx.x; idx < 64 * 64; idx += 256) {
            int r = idx >> 6, c = idx & 63;             // c fast -> coalesced read of W2 row
            tile[c][r] = f2bf(W2[(size_t)(k0 + r) * H_DIM + n0 + c]);
        }
        __syncthreads();
        for (int idx = threadIdx.x; idx < 64 * 64; idx += 256) {
            int r = idx >> 6, c = idx & 63;             // c fast -> coalesced write of W2T row
            W2T[(size_t)(n0 + r) * H_DIM + k0 + c] = tile[r][c];
        }
    }
}

// ---------------- Kernel 2: fused GEMM + tanh + @W3 row-reduce ----------------
// Proven R0 body (BK=64 single-buffer, 128x64 tile, 24 KB LDS, 4 blocks/CU) +
// R5's 2D XCD-region swizzle (WIN: FETCH 69.8->33.0 MB, 55->52.7 us).
// Structural ladder is exhausted: R1 128^2 (2/CU, 77us), R2 BK=64 dbuf (3/CU,
// 85us), R3/R4 BK=32 dbuf (73.7us even at 0 conflicts + 4/CU) all regressed.
// This round: tanh_fast in the epilogue — 32 OCML tanhf/thread (~150 cy each,
// serialized after the K-loop) ~= 6-8 us of the 53; fast version is ~4 instrs.
// XCD-region swizzle: x=bid&7 (HW round-robin), idx=bid>>3; by=(x>>1)*8+(idx>>4),
// bx=(x&1)*16+(idx&15) -> 8 by x 16 bx region per XCD, footprint 8 MB < L2.
// Staging swizzle (proven, 0 conflicts): lane l -> row (l>>3), data chunk (l&7)^(l>>3);
// LDS elem(r,k) @ r*64 + ((k>>3)^(r&7))*8 + (k&7); fragment slot cs=(s*4+quad)^(lane16&7).
#define BK 64
__global__ __launch_bounds__(256, 4) void gemm_fused(
    const unsigned short* __restrict__ A,    // 4096 x 2048 bf16 (h)
    const unsigned short* __restrict__ BT,   // 2048 x 2048 bf16 (W2^T, N x K)
    const float* __restrict__ b2, const float* __restrict__ W3,
    float* __restrict__ rowsum) {
    __shared__ __align__(16) unsigned short As[128 * BK];   // 16 KB
    __shared__ __align__(16) unsigned short Bs[64 * BK];    // 8 KB
    const int K = H_DIM;
    const int t = threadIdx.x;
    const int w = t >> 6, l = t & 63;
    const int lane16 = l & 15, quad = l >> 4;
    const int wr = w >> 1, wc = w & 1;                      // 2x2 waves over 128x64

    // XCD-region swizzle (8 by x 16 bx per XCD)
    const int bid = blockIdx.x;
    const int xcd = bid & 7, idx = bid >> 3;
    const int by = (xcd >> 1) * 8 + (idx >> 4);
    const int bx = (xcd & 1) * 16 + (idx & 15);
    const int rowBase = by * 128;
    const int colBase = bx * 64;

    // per-lane staging offset within an 8-row group (elements)
    const int sRow = l >> 3;                   // 0..7
    const int sChunk = (l & 7) ^ sRow;         // swizzled data chunk
    const size_t laneOff = (size_t)sRow * K + sChunk * 8;

    // wave w stages A rows [w*32, w*32+32) in 4 instrs, B rows [w*16, w*16+16) in 2
    const unsigned short* aBase = A  + (size_t)(rowBase + w * 32) * K + laneOff;
    const unsigned short* bBase = BT + (size_t)(colBase + w * 16) * K + laneOff;

    floatx4 acc[4][2];
    floatx4 zero = {0.f, 0.f, 0.f, 0.f};
#pragma unroll
    for (int i = 0; i < 4; ++i)
#pragma unroll
        for (int j = 0; j < 2; ++j) acc[i][j] = zero;

    for (int k0 = 0; k0 < K; k0 += BK) {
        __syncthreads();          // prior iteration's ds_reads done; LDS reusable
#pragma unroll
        for (int i = 0; i < 4; ++i)
            __builtin_amdgcn_global_load_lds(
                (const AS1 void*)(aBase + (size_t)i * 8 * K + k0),
                (AS3 void*)(As + (w * 32 + i * 8) * 64), 16, 0, 0);
#pragma unroll
        for (int i = 0; i < 2; ++i)
            __builtin_amdgcn_global_load_lds(
                (const AS1 void*)(bBase + (size_t)i * 8 * K + k0),
                (AS3 void*)(Bs + (w * 16 + i * 8) * 64), 16, 0, 0);
        __syncthreads();          // vmcnt(0) drain: tile ready

#pragma unroll
        for (int s = 0; s < 2; ++s) {   // two 16x16x32 k-steps within BK=64
            const int cs = (s * 4 + quad) ^ (lane16 & 7);
            bf16x8 af[4], bfr[2];
#pragma unroll
            for (int mi = 0; mi < 4; ++mi)
                af[mi] = *(const bf16x8*)(As + (wr * 64 + mi * 16 + lane16) * 64 + cs * 8);
#pragma unroll
            for (int ni = 0; ni < 2; ++ni)
                bfr[ni] = *(const bf16x8*)(Bs + (wc * 32 + ni * 16 + lane16) * 64 + cs * 8);
#pragma unroll
            for (int mi = 0; mi < 4; ++mi)
#pragma unroll
                for (int ni = 0; ni < 2; ++ni)
                    acc[mi][ni] = __builtin_amdgcn_mfma_f32_16x16x32_bf16(
                        af[mi], bfr[ni], acc[mi][ni], 0, 0, 0);
        }
    }

    // Epilogue: C/D layout col=lane&15, row=quad*4+reg
    const int rowG = rowBase + wr * 64;
#pragma unroll
    for (int mi = 0; mi < 4; ++mi) {
#pragma unroll
        for (int r = 0; r < 4; ++r) {
            float s = 0.f;
#pragma unroll
            for (int ni = 0; ni < 2; ++ni) {
                int col = colBase + wc * 32 + ni * 16 + lane16;
                float v = acc[mi][ni][r] + b2[col];
                s += tanh_fast(v) * W3[col];
            }
#pragma unroll
            for (int off = 1; off < 16; off <<= 1) s += __shfl_xor(s, off, 64);
            if (lane16 == 0)
                atomicAdd(&rowsum[rowG + mi * 16 + quad * 4 + r], s);
        }
    }
}

// ---------------- Kernel 3: spline gather, 2 points/thread, fused u=3*tanh(rowsum+b3) ----------------
__device__ __forceinline__ float spline_eval(const float* us, float ptx, float pty) {
    float x = (ptx + 1.0f) * 0.5f;
    float px = x * 62.0f, py = pty * 62.0f;
    float fx = floorf(px), fy = floorf(py);
    int posx = min((int)fx + 1, 62);
    int posy = min((int)fy + 1, 62);
    float tx = px - fx, ty = py - fy;
    float bx0 = 0.5f * (1.f - tx) * (1.f - tx);
    float bx1 = -tx * tx + tx + 0.5f;
    float bx2 = 0.5f * tx * tx;
    float by0 = 0.5f * (1.f - ty) * (1.f - ty);
    float by1 = -ty * ty + ty + 0.5f;
    float by2 = 0.5f * ty * ty;
    const float* r0 = &us[(posx - 1) * 64 + (posy - 1)];
    const float* r1 = r0 + 64;
    const float* r2 = r1 + 64;
    float s0 = r0[0] * by0 + r0[1] * by1 + r0[2] * by2;
    float s1 = r1[0] * by0 + r1[1] * by1 + r1[2] * by2;
    float s2 = r2[0] * by0 + r2[1] * by1 + r2[2] * by2;
    return bx0 * s0 + bx1 * s1 + bx2 * s2;
}

__global__ void spline_kernel(const float4* __restrict__ pts,
                              const float* __restrict__ rowsum,
                              const float* __restrict__ b3,
                              float2* __restrict__ out, int npairs) {
    __shared__ float us[4096];
    float bias = b3[0];
    for (int i = threadIdx.x; i < 4096; i += blockDim.x)
        us[i] = 3.0f * tanh_fast(rowsum[i] + bias);
    __syncthreads();
    int stride = gridDim.x * blockDim.x;
    for (int idx = blockIdx.x * blockDim.x + threadIdx.x; idx < npairs; idx += stride) {
        float4 p2 = pts[idx];     // two points
        float2 o;
        o.x = spline_eval(us, p2.x, p2.y);
        o.y = spline_eval(us, p2.z, p2.w);
        out[idx] = o;
    }
}

extern "C" void kernel_launch(void* const* d_in, const int* in_sizes, int n_in,
                              void* d_out, int out_size, void* d_ws, size_t ws_size,
                              hipStream_t stream) {
    const float* points = (const float*)d_in[0];
    const float* W1 = (const float*)d_in[1];
    const float* b1 = (const float*)d_in[2];
    const float* W2 = (const float*)d_in[3];
    const float* b2 = (const float*)d_in[4];
    const float* W3 = (const float*)d_in[5];
    const float* b3 = (const float*)d_in[6];
    float* out = (float*)d_out;

    char* ws = (char*)d_ws;
    unsigned short* hbf = (unsigned short*)ws;                        // 16777216 B
    unsigned short* w2t = (unsigned short*)(ws + 16777216);           //  8388608 B
    float* rowsum = (float*)(ws + 25165824);                          //    16384 B

    prep_all<<<8192 + 1024, 256, 0, stream>>>(W1, b1, W2, hbf, w2t, rowsum);
    gemm_fused<<<1024, 256, 0, stream>>>(hbf, w2t, b2, W3, rowsum);
    spline_kernel<<<1024, 256, 0, stream>>>((const float4*)points, rowsum, b3,
                                            (float2*)out, NPTS / 2);
}